// Round 5
// baseline (245.235 us; speedup 1.0000x reference)
//
#include <hip/hip_runtime.h>
#include <math.h>

#define ALPHA 50.0f
#define EPS 1e-12f

constexpr int N = 64, C = 128, P = 4096, K = 64;
constexpr int NCH2 = 8;           // partial groups (one per block per n)

typedef short short8_t __attribute__((ext_vector_type(8)));
typedef short short4_t __attribute__((ext_vector_type(4)));
typedef float f4 __attribute__((ext_vector_type(4)));
typedef unsigned int u32x4 __attribute__((ext_vector_type(4)));
typedef unsigned int u32x2 __attribute__((ext_vector_type(2)));

__device__ __forceinline__ unsigned short f2bf(float f) {
    union { float f; unsigned u; } v; v.f = f;
    unsigned r = (v.u + 0x7FFFu + ((v.u >> 16) & 1u)) >> 16;   // RNE
    return (unsigned short)r;
}

// packed f32x2 -> bf16x2 (RNE), single VALU op
__device__ __forceinline__ unsigned cvtpk(float lo, float hi) {
    unsigned r;
    asm("v_cvt_pk_bf16_f32 %0, %1, %2" : "=v"(r) : "v"(lo), "v"(hi));
    return r;
}

// __syncthreads() minus the vmcnt(0) drain: LDS-visibility barrier only.
__device__ __forceinline__ void bar_lds() {
    asm volatile("s_waitcnt lgkmcnt(0)" ::: "memory");
    __builtin_amdgcn_s_barrier();
}

// ---------------------------------------------------------------------------
// Fused: 512 blocks x 512 threads (8 waves). Block = (n, 512-px strip),
// 8 chunks of 64 px. 16 waves/CU (2 blocks, LDS 72,704 B each).
// Wave roles: w = tid>>6; kt = w>>1 (k-16-tile), h = w&1 (px/c half).
// Per chunk, 3 barriers:
//   B0: LDS reuse guard
//   staging (ssq partials, bf16 xsT swizzled + xsN)        [B1]
//   GEMM1 + per-wave redundant invs + logits(NT) + exp->saf + denom  [B3]
//   S + sa2 (shfl rfin)                                    [B4]
//   GEMM2 (in-chunk)
// ---------------------------------------------------------------------------
__global__ __launch_bounds__(512, 4) void k_fused(
    const float* __restrict__ x, const float* __restrict__ W,
    const float* __restrict__ bias, float* __restrict__ logits,
    float* __restrict__ vlad_part, float* __restrict__ Spart,
    float* __restrict__ ss2acc)
{
    __shared__ __align__(16) char smem[72704];
    unsigned short* xsT  = (unsigned short*)smem;            // [64][136] sh, 17408 B
    unsigned short* xsN  = (unsigned short*)(smem + 17408);  // [128][76] sh, 19456 B
    float*          saf  = (float*)(smem + 36864);           // [64][68] f32, 17408 B
    unsigned short* sa2s = (unsigned short*)(smem + 54272);  // [64][72] sh, 9216 B
    float*          denom= (float*)(smem + 63488);           // [32][68] f32, 8704 B (rd2/red overlay)
    float*          invs = (float*)(smem + 72192);           // 64 f
    float*          biass= (float*)(smem + 72448);           // 64 f
    float*          Wl   = (float*)smem;                     // prologue: [128][68] f32 = 34816 B
    float*          rd2  = denom;                            // staging ssq scratch [64][33] f32
    float*          red  = denom;                            // epilogue reduce [512] f32

    const int tid  = threadIdx.x;
    const int n    = blockIdx.x >> 3;
    const int blk8 = blockIdx.x & 7;
    const int pbase = blk8 * 512;

    const int w = tid >> 6, lane = tid & 63;
    const int q = lane >> 4, l15 = lane & 15, l4 = l15 >> 2;
    const int kt = w >> 1, h = w & 1;
    const int pxg = tid & 15, cgrp = tid >> 4;   // staging roles

    if (blockIdx.x == 0 && tid < 64) ss2acc[tid] = 0.f;  // k_post1 accumulator

    const float* xrow = x + (size_t)n * C * P + pbase + 4 * pxg;
    float4 va[4], vb[4];
    short8_t af[4];
    float bz[4];

    // ---- prologue: column-normalized W fragments from Wl ----
    {
        #pragma unroll
        for (int j = 0; j < 4; ++j)          // chunk-0 x prefetch first
            va[j] = *(const float4*)&xrow[(size_t)(4 * cgrp + j) * P];
        if (tid < K) biass[tid] = bias[tid] * ALPHA;
        #pragma unroll
        for (int pass = 0; pass < 2; ++pass) {
            float4 wv[4];
            #pragma unroll
            for (int it = 0; it < 4; ++it)
                wv[it] = *(const float4*)&W[(size_t)(tid + (4 * pass + it) * 512) * 4];
            #pragma unroll
            for (int it = 0; it < 4; ++it) {
                const int idx4 = tid + (4 * pass + it) * 512;   // float4 idx into W[C][K]
                *(float4*)&Wl[(idx4 >> 4) * 68 + (idx4 & 15) * 4] = wv[it];
            }
        }
        bar_lds();
        {   // column sum-of-squares: 64 k x 8 parts of 16 rows
            float s = 0.f;
            #pragma unroll
            for (int i = 0; i < 16; ++i) {
                float v = Wl[(w * 16 + i) * 68 + lane];
                s = fmaf(v, v, s);
            }
            red[tid] = s;
        }
        bar_lds();
        if (tid < 64) {
            float s = 0.f;
            #pragma unroll
            for (int p = 0; p < 8; ++p) s += red[64 * p + tid];
            invs[tid] = 1.0f / fmaxf(sqrtf(s), EPS);
        }
        bar_lds();
        {   // af[c0][j] = bf16(Wl[c][k] * cinv[k]), k = 16*kt + l15
            const float cv = invs[16 * kt + l15];
            #pragma unroll
            for (int c0 = 0; c0 < 4; ++c0)
                #pragma unroll
                for (int j = 0; j < 8; ++j)
                    af[c0][j] = (short)f2bf(
                        Wl[(c0 * 32 + 8 * q + j) * 68 + 16 * kt + l15] * cv);
            #pragma unroll
            for (int r = 0; r < 4; ++r) bz[r] = biass[16 * kt + 4 * q + r];
        }
        bar_lds();   // drain af/bz reads before staging(0) overwrites Wl
    }

    f4 acc2[4];
    #pragma unroll
    for (int ct = 0; ct < 4; ++ct) acc2[ct] = (f4){0.f, 0.f, 0.f, 0.f};
    float Sreg = 0.f;

    const int pbT = (cgrp >> 1) ^ (pxg & 7);   // write-side xsT block swizzle

    for (int ch = 0; ch < 8; ++ch) {
        if (ch < 7) {                           // prefetch next chunk
            const float* xb = xrow + (ch + 1) * 64;
            #pragma unroll
            for (int j = 0; j < 4; ++j)
                vb[j] = *(const float4*)&xb[(size_t)(4 * cgrp + j) * P];
        }
        bar_lds();                              // B0: LDS reuse guard
        const float* vf = (const float*)va;

        // ---- staging: ssq partials + bf16 xsT (swizzled) + bf16 xsN ----
        {
            float pss[4] = {0.f, 0.f, 0.f, 0.f};
            #pragma unroll
            for (int j = 0; j < 4; ++j)
                #pragma unroll
                for (int i = 0; i < 4; ++i)
                    pss[i] = fmaf(vf[j * 4 + i], vf[j * 4 + i], pss[i]);
            #pragma unroll
            for (int i = 0; i < 4; ++i) rd2[(4 * pxg + i) * 33 + cgrp] = pss[i];

            #pragma unroll
            for (int i = 0; i < 4; ++i) {       // xsT: px-row, 4 contiguous c
                u32x2 t2;
                t2[0] = cvtpk(vf[0 * 4 + i], vf[1 * 4 + i]);
                t2[1] = cvtpk(vf[2 * 4 + i], vf[3 * 4 + i]);
                *(u32x2*)&xsT[(4 * pxg + i) * 136 + pbT * 8 + (cgrp & 1) * 4] = t2;
            }
            #pragma unroll
            for (int j = 0; j < 4; ++j) {       // xsN: c-row, 4 contiguous px
                u32x2 t2;
                t2[0] = cvtpk(vf[j * 4 + 0], vf[j * 4 + 1]);
                t2[1] = cvtpk(vf[j * 4 + 2], vf[j * 4 + 3]);
                *(u32x2*)&xsN[(4 * cgrp + j) * 76 + 4 * pxg] = t2;
            }
        }
        bar_lds();                              // B1

        // ---- GEMM1 + redundant invs + logits(NT) + exp->saf + denom ----
        float myinv = 0.f;
        {   // per-wave invs for this wave's 32 px; also publish to LDS
            const int pxL = h * 32 + ((lane >> 4) & 1) * 16 + l15;
            const int gb  = (lane >> 5) * 16;
            float s = 0.f;
            #pragma unroll
            for (int g = 0; g < 16; ++g) s += rd2[pxL * 33 + gb + g];
            s += __shfl_xor(s, 32);
            myinv = 1.0f / fmaxf(sqrtf(s), EPS);
            if (lane < 32) invs[pxL] = myinv;   // dup writes, identical values
        }
        f4 acc1[2];
        acc1[0] = (f4){0.f, 0.f, 0.f, 0.f};
        acc1[1] = (f4){0.f, 0.f, 0.f, 0.f};
        __builtin_amdgcn_s_setprio(1);
        #pragma unroll
        for (int c0 = 0; c0 < 4; ++c0)
            #pragma unroll
            for (int p2 = 0; p2 < 2; ++p2) {
                const int pxt = 2 * h + p2;
                const int pb = (4 * c0 + q) ^ (4 * p2 + l4);
                short8_t bf = *(const short8_t*)&xsT[(pxt * 16 + l15) * 136 + pb * 8];
                acc1[p2] = __builtin_amdgcn_mfma_f32_16x16x32_bf16(af[c0], bf, acc1[p2], 0, 0, 0);
            }
        __builtin_amdgcn_s_setprio(0);
        {
            const int p0 = pbase + ch * 64;
            float* lgp = logits + (size_t)n * K * P + p0;
            float ivv[2];
            ivv[0] = __shfl(myinv, l15);
            ivv[1] = __shfl(myinv, 16 + l15);
            #pragma unroll
            for (int p2 = 0; p2 < 2; ++p2) {
                const int pxl = (2 * h + p2) * 16 + l15;
                const float iv = ivv[p2];
                float psum = 0.f;
                #pragma unroll
                for (int r = 0; r < 4; ++r) {
                    const int k = 16 * kt + 4 * q + r;
                    const float lv = acc1[p2][r] * iv;
                    __builtin_nontemporal_store(lv, &lgp[(size_t)k * P + pxl]);
                    const float e = __expf(fmaf(lv, ALPHA, bz[r]));
                    saf[k * 68 + pxl] = e;
                    psum += e;
                }
                denom[(4 * w + q) * 68 + pxl] = psum;
            }
        }
        bar_lds();                              // B3

        // ---- S + sa2 (thread = (k-row = lane, px-seg = w), 8 px each) ----
        {
            float dinv = 0.f;
            if (lane < 8) {
                const int px = 8 * w + lane;
                const int H = px >> 5;
                float dd = 0.f;
                #pragma unroll
                for (int t = 0; t < 4; ++t)
                    #pragma unroll
                    for (int qq = 0; qq < 4; ++qq)
                        dd += denom[(8 * t + 4 * H + qq) * 68 + px];
                dinv = 1.0f / dd;
            }
            const float* sp = &saf[lane * 68 + 8 * w];
            const f4 ivA = *(const f4*)&invs[8 * w];
            const f4 ivB = *(const f4*)&invs[8 * w + 4];
            float s = 0.f;
            unsigned pk[4];
            #pragma unroll
            for (int m = 0; m < 2; ++m) {
                f4 e = *(const f4*)&sp[4 * m];
                const f4 iv = m ? ivB : ivA;
                const float r0 = __shfl(dinv, 4 * m + 0);
                const float r1 = __shfl(dinv, 4 * m + 1);
                const float r2 = __shfl(dinv, 4 * m + 2);
                const float r3 = __shfl(dinv, 4 * m + 3);
                s += e[0] * r0; s += e[1] * r1;
                s += e[2] * r2; s += e[3] * r3;
                const float v0 = e[0] * (r0 * iv[0]);
                const float v1 = e[1] * (r1 * iv[1]);
                const float v2 = e[2] * (r2 * iv[2]);
                const float v3 = e[3] * (r3 * iv[3]);
                pk[2 * m]     = cvtpk(v0, v1);
                pk[2 * m + 1] = cvtpk(v2, v3);
            }
            Sreg += s;
            *(u32x4*)&sa2s[lane * 72 + 8 * w] = (u32x4){pk[0], pk[1], pk[2], pk[3]};
        }
        bar_lds();                              // B4

        // ---- GEMM2: acc2[kt-tile][c-tile] += sa2 . x_raw ----
        {
            short8_t a2[2];
            #pragma unroll
            for (int kit = 0; kit < 2; ++kit)
                a2[kit] = *(const short8_t*)&sa2s[(16 * kt + l15) * 72 + kit * 32 + 8 * q];
            __builtin_amdgcn_s_setprio(1);
            #pragma unroll
            for (int ctl = 0; ctl < 4; ++ctl) {
                const int ct = 4 * h + ctl;
                #pragma unroll
                for (int kit = 0; kit < 2; ++kit) {
                    const unsigned short* bp = &xsN[(ct * 16 + l15) * 76 + kit * 32 + 8 * q];
                    short4_t b0 = *(const short4_t*)bp;
                    short4_t b1 = *(const short4_t*)(bp + 4);
                    short8_t bb;
                    bb[0] = b0[0]; bb[1] = b0[1]; bb[2] = b0[2]; bb[3] = b0[3];
                    bb[4] = b1[0]; bb[5] = b1[1]; bb[6] = b1[2]; bb[7] = b1[3];
                    acc2[ctl] = __builtin_amdgcn_mfma_f32_16x16x32_bf16(a2[kit], bb, acc2[ctl], 0, 0, 0);
                }
            }
            __builtin_amdgcn_s_setprio(0);
        }

        if (ch < 7) {
            #pragma unroll
            for (int j = 0; j < 4; ++j) va[j] = vb[j];
        }
    }

    // ---- epilogue: per-block partials (no atomics) ----
    float* vp = vlad_part + ((size_t)blk8 * N + n) * (size_t)(K * C);
    #pragma unroll
    for (int ctl = 0; ctl < 4; ++ctl)
        #pragma unroll
        for (int r = 0; r < 4; ++r)
            vp[(16 * kt + 4 * q + r) * C + (4 * h + ctl) * 16 + l15] = acc2[ctl][r];

    __syncthreads();                 // denom region reused as red[512]
    red[tid] = Sreg;
    __syncthreads();
    if (tid < 64) {
        float s = 0.f;
        #pragma unroll
        for (int p = 0; p < 8; ++p) s += red[64 * p + tid];
        Spart[((size_t)blk8 * N + n) * K + tid] = s;
    }
}

// ---------------------------------------------------------------------------
// Post 1: reduce 8 partials, subtract W*S, intra-norm (c), write un-scaled
// rows; accumulate global-norm ss2 per n via one atomic per block.
// ---------------------------------------------------------------------------
__global__ __launch_bounds__(256) void k_post1(
    const float* __restrict__ vlad_part, const float* __restrict__ W,
    const float* __restrict__ Spart, float* __restrict__ out,
    float* __restrict__ ss2acc)
{
    __shared__ float red[16];
    const int tid = threadIdx.x;
    const int n  = blockIdx.x >> 2;
    const int kq = blockIdx.x & 3;
    const int kl = tid >> 4;           // 0..15
    const int ci = tid & 15;           // 0..15
    const int k  = kq * 16 + kl;
    const int c0 = ci * 8;

    float Sk = 0.f;
    #pragma unroll
    for (int ch = 0; ch < NCH2; ++ch) Sk += Spart[(size_t)(ch * N + n) * K + k];

    float v[8];
    #pragma unroll
    for (int l = 0; l < 8; ++l) v[l] = 0.f;
    #pragma unroll
    for (int ch = 0; ch < NCH2; ++ch) {
        const float* vp = vlad_part + ((size_t)(ch * N + n) * K + k) * C + c0;
        float4 a = *(const float4*)&vp[0];
        float4 b = *(const float4*)&vp[4];
        v[0] += a.x; v[1] += a.y; v[2] += a.z; v[3] += a.w;
        v[4] += b.x; v[5] += b.y; v[6] += b.z; v[7] += b.w;
    }

    float ss = 0.f;
    #pragma unroll
    for (int l = 0; l < 8; ++l) {
        float val = v[l] - W[(size_t)(c0 + l) * K + k] * Sk;
        v[l] = val;
        ss = fmaf(val, val, ss);
    }
    ss += __shfl_xor(ss, 1);
    ss += __shfl_xor(ss, 2);
    ss += __shfl_xor(ss, 4);
    ss += __shfl_xor(ss, 8);
    const float inv1 = 1.0f / fmaxf(sqrtf(ss), EPS);
    float ss2 = 0.f;
    #pragma unroll
    for (int l = 0; l < 8; ++l) { v[l] *= inv1; ss2 = fmaf(v[l], v[l], ss2); }
    ss2 += __shfl_xor(ss2, 1);
    ss2 += __shfl_xor(ss2, 2);
    ss2 += __shfl_xor(ss2, 4);
    ss2 += __shfl_xor(ss2, 8);
    if (ci == 0) red[kl] = ss2;
    __syncthreads();
    if (tid == 0) {
        float t = 0.f;
        #pragma unroll
        for (int i = 0; i < 16; ++i) t += red[i];
        atomicAdd(&ss2acc[n], t);
    }

    float* op = out + (size_t)n * K * C + (size_t)k * C + c0;
    *(float4*)&op[0] = (float4){v[0], v[1], v[2], v[3]};
    *(float4*)&op[4] = (float4){v[4], v[5], v[6], v[7]};
}

// ---------------------------------------------------------------------------
// Post 2: global L2 rescale in place. grid = N*4.
// ---------------------------------------------------------------------------
__global__ __launch_bounds__(256) void k_post2(
    float* __restrict__ out, const float* __restrict__ ss2acc)
{
    const int n   = blockIdx.x >> 2;
    const int seg = blockIdx.x & 3;
    const float inv2 = 1.0f / fmaxf(sqrtf(ss2acc[n]), EPS);
    float* p = out + (size_t)n * K * C + (size_t)seg * 2048 + (size_t)threadIdx.x * 8;
    float4 a = *(const float4*)&p[0];
    float4 b = *(const float4*)&p[4];
    a.x *= inv2; a.y *= inv2; a.z *= inv2; a.w *= inv2;
    b.x *= inv2; b.y *= inv2; b.z *= inv2; b.w *= inv2;
    *(float4*)&p[0] = a;
    *(float4*)&p[4] = b;
}

// ---------------------------------------------------------------------------
extern "C" void kernel_launch(void* const* d_in, const int* in_sizes, int n_in,
                              void* d_out, int out_size, void* d_ws, size_t ws_size,
                              hipStream_t stream)
{
    const float* x    = (const float*)d_in[0];
    const float* W    = (const float*)d_in[1];
    const float* bias = (const float*)d_in[2];

    float* out_vlad   = (float*)d_out;                       // N*K*C
    float* out_logits = (float*)d_out + (size_t)N * K * C;   // N*K*P

    float* ss2acc     = (float*)((char*)d_ws + 16384);                  // 256 B
    float* Spart      = (float*)((char*)d_ws + 32768);                  // 128 KiB
    float* vlad_part  = (float*)((char*)d_ws + 32768 + 131072);         // 16 MiB

    k_fused<<<dim3(N * NCH2), dim3(512), 0, stream>>>(
        x, W, bias, out_logits, vlad_part, Spart, ss2acc);
    k_post1<<<dim3(N * 4), dim3(256), 0, stream>>>(vlad_part, W, Spart, out_vlad, ss2acc);
    k_post2<<<dim3(N * 4), dim3(256), 0, stream>>>(out_vlad, ss2acc);
}

// Round 6
// 237.678 us; speedup vs baseline: 1.0318x; 1.0318x over previous
//
#include <hip/hip_runtime.h>
#include <math.h>

#define ALPHA 50.0f
#define EPS 1e-12f

constexpr int N = 64, C = 128, P = 4096, K = 64;
constexpr int NCH2 = 8;           // partial groups (one per block per n)

typedef short short8_t __attribute__((ext_vector_type(8)));
typedef short short4_t __attribute__((ext_vector_type(4)));
typedef float f4 __attribute__((ext_vector_type(4)));
typedef unsigned int u32x4 __attribute__((ext_vector_type(4)));
typedef unsigned int u32x2 __attribute__((ext_vector_type(2)));

__device__ __forceinline__ unsigned short f2bf(float f) {
    union { float f; unsigned u; } v; v.f = f;
    unsigned r = (v.u + 0x7FFFu + ((v.u >> 16) & 1u)) >> 16;   // RNE
    return (unsigned short)r;
}

// packed f32x2 -> bf16x2 (RNE), single VALU op
__device__ __forceinline__ unsigned cvtpk(float lo, float hi) {
    unsigned r;
    asm("v_cvt_pk_bf16_f32 %0, %1, %2" : "=v"(r) : "v"(lo), "v"(hi));
    return r;
}

// __syncthreads() minus the vmcnt(0) drain: LDS-visibility barrier only.
__device__ __forceinline__ void bar_lds() {
    asm volatile("s_waitcnt lgkmcnt(0)" ::: "memory");
    __builtin_amdgcn_s_barrier();
}

// ---------------------------------------------------------------------------
// Fused: 512 blocks x 512 threads (8 waves). Block = (n, 512-px strip),
// 8 chunks of 64 px. 16 waves/CU (2 blocks/CU, LDS 72,704 B each).
// __launch_bounds__(512,2): VGPR cap 128 (round 5's (512,4) capped at 64
// and spilled -> scratch traffic; this is the fix under test).
// ---------------------------------------------------------------------------
__global__ __launch_bounds__(512, 2) void k_fused(
    const float* __restrict__ x, const float* __restrict__ W,
    const float* __restrict__ bias, float* __restrict__ logits,
    float* __restrict__ vlad_part, float* __restrict__ Spart,
    float* __restrict__ ss2acc)
{
    __shared__ __align__(16) char smem[72704];
    unsigned short* xsT  = (unsigned short*)smem;            // [64][136] sh, 17408 B
    unsigned short* xsN  = (unsigned short*)(smem + 17408);  // [128][76] sh, 19456 B
    float*          saf  = (float*)(smem + 36864);           // [64][68] f32, 17408 B
    unsigned short* sa2s = (unsigned short*)(smem + 54272);  // [64][72] sh, 9216 B
    float*          denom= (float*)(smem + 63488);           // [32][68] f32, 8704 B (rd2/red overlay)
    float*          invs = (float*)(smem + 72192);           // 64 f
    float*          biass= (float*)(smem + 72448);           // 64 f
    float*          Wl   = (float*)smem;                     // prologue: [128][68] f32 = 34816 B
    float*          rd2  = denom;                            // staging ssq scratch [64][33] f32
    float*          red  = denom;                            // epilogue reduce [512] f32

    const int tid  = threadIdx.x;
    const int n    = blockIdx.x >> 3;
    const int blk8 = blockIdx.x & 7;
    const int pbase = blk8 * 512;

    const int w = tid >> 6, lane = tid & 63;
    const int q = lane >> 4, l15 = lane & 15, l4 = l15 >> 2;
    const int kt = w >> 1, h = w & 1;
    const int pxg = tid & 15, cgrp = tid >> 4;   // staging roles

    if (blockIdx.x == 0 && tid < 64) ss2acc[tid] = 0.f;  // k_post1 accumulator

    const float* xrow = x + (size_t)n * C * P + pbase + 4 * pxg;
    float4 va[4], vb[4];
    short8_t af[4];
    float bz[4];

    // ---- prologue: column-normalized W fragments from Wl ----
    {
        #pragma unroll
        for (int j = 0; j < 4; ++j)          // chunk-0 x prefetch first
            va[j] = *(const float4*)&xrow[(size_t)(4 * cgrp + j) * P];
        if (tid < K) biass[tid] = bias[tid] * ALPHA;
        #pragma unroll
        for (int pass = 0; pass < 2; ++pass) {
            float4 wv[4];
            #pragma unroll
            for (int it = 0; it < 4; ++it)
                wv[it] = *(const float4*)&W[(size_t)(tid + (4 * pass + it) * 512) * 4];
            #pragma unroll
            for (int it = 0; it < 4; ++it) {
                const int idx4 = tid + (4 * pass + it) * 512;   // float4 idx into W[C][K]
                *(float4*)&Wl[(idx4 >> 4) * 68 + (idx4 & 15) * 4] = wv[it];
            }
        }
        bar_lds();
        {   // column sum-of-squares: 64 k x 8 parts of 16 rows
            float s = 0.f;
            #pragma unroll
            for (int i = 0; i < 16; ++i) {
                float v = Wl[(w * 16 + i) * 68 + lane];
                s = fmaf(v, v, s);
            }
            red[tid] = s;
        }
        bar_lds();
        if (tid < 64) {
            float s = 0.f;
            #pragma unroll
            for (int p = 0; p < 8; ++p) s += red[64 * p + tid];
            invs[tid] = 1.0f / fmaxf(sqrtf(s), EPS);
        }
        bar_lds();
        {   // af[c0][j] = bf16(Wl[c][k] * cinv[k]), k = 16*kt + l15
            const float cv = invs[16 * kt + l15];
            #pragma unroll
            for (int c0 = 0; c0 < 4; ++c0)
                #pragma unroll
                for (int j = 0; j < 8; ++j)
                    af[c0][j] = (short)f2bf(
                        Wl[(c0 * 32 + 8 * q + j) * 68 + 16 * kt + l15] * cv);
            #pragma unroll
            for (int r = 0; r < 4; ++r) bz[r] = biass[16 * kt + 4 * q + r];
        }
        bar_lds();   // drain af/bz reads before staging(0) overwrites Wl
    }

    f4 acc2[4];
    #pragma unroll
    for (int ct = 0; ct < 4; ++ct) acc2[ct] = (f4){0.f, 0.f, 0.f, 0.f};
    float Sreg = 0.f;

    const int pbT = (cgrp >> 1) ^ (pxg & 7);   // write-side xsT block swizzle

    for (int ch = 0; ch < 8; ++ch) {
        if (ch < 7) {                           // prefetch next chunk
            const float* xb = xrow + (ch + 1) * 64;
            #pragma unroll
            for (int j = 0; j < 4; ++j)
                vb[j] = *(const float4*)&xb[(size_t)(4 * cgrp + j) * P];
        }
        bar_lds();                              // B0: LDS reuse guard
        const float* vf = (const float*)va;

        // ---- staging: ssq partials + bf16 xsT (swizzled) + bf16 xsN ----
        {
            float pss[4] = {0.f, 0.f, 0.f, 0.f};
            #pragma unroll
            for (int j = 0; j < 4; ++j)
                #pragma unroll
                for (int i = 0; i < 4; ++i)
                    pss[i] = fmaf(vf[j * 4 + i], vf[j * 4 + i], pss[i]);
            #pragma unroll
            for (int i = 0; i < 4; ++i) rd2[(4 * pxg + i) * 33 + cgrp] = pss[i];

            #pragma unroll
            for (int i = 0; i < 4; ++i) {       // xsT: px-row, 4 contiguous c
                u32x2 t2;
                t2[0] = cvtpk(vf[0 * 4 + i], vf[1 * 4 + i]);
                t2[1] = cvtpk(vf[2 * 4 + i], vf[3 * 4 + i]);
                *(u32x2*)&xsT[(4 * pxg + i) * 136 + pbT * 8 + (cgrp & 1) * 4] = t2;
            }
            #pragma unroll
            for (int j = 0; j < 4; ++j) {       // xsN: c-row, 4 contiguous px
                u32x2 t2;
                t2[0] = cvtpk(vf[j * 4 + 0], vf[j * 4 + 1]);
                t2[1] = cvtpk(vf[j * 4 + 2], vf[j * 4 + 3]);
                *(u32x2*)&xsN[(4 * cgrp + j) * 76 + 4 * pxg] = t2;
            }
        }
        bar_lds();                              // B1

        // ---- GEMM1 + redundant invs + logits(NT) + exp->saf + denom ----
        float myinv = 0.f;
        {   // per-wave invs for this wave's 32 px; also publish to LDS
            const int pxL = h * 32 + ((lane >> 4) & 1) * 16 + l15;
            const int gb  = (lane >> 5) * 16;
            float s = 0.f;
            #pragma unroll
            for (int g = 0; g < 16; ++g) s += rd2[pxL * 33 + gb + g];
            s += __shfl_xor(s, 32);
            myinv = 1.0f / fmaxf(sqrtf(s), EPS);
            if (lane < 32) invs[pxL] = myinv;   // dup writes, identical values
        }
        f4 acc1[2];
        acc1[0] = (f4){0.f, 0.f, 0.f, 0.f};
        acc1[1] = (f4){0.f, 0.f, 0.f, 0.f};
        __builtin_amdgcn_s_setprio(1);
        #pragma unroll
        for (int c0 = 0; c0 < 4; ++c0)
            #pragma unroll
            for (int p2 = 0; p2 < 2; ++p2) {
                const int pxt = 2 * h + p2;
                const int pb = (4 * c0 + q) ^ (4 * p2 + l4);
                short8_t bf = *(const short8_t*)&xsT[(pxt * 16 + l15) * 136 + pb * 8];
                acc1[p2] = __builtin_amdgcn_mfma_f32_16x16x32_bf16(af[c0], bf, acc1[p2], 0, 0, 0);
            }
        __builtin_amdgcn_s_setprio(0);
        {
            const int p0 = pbase + ch * 64;
            float* lgp = logits + (size_t)n * K * P + p0;
            float ivv[2];
            ivv[0] = __shfl(myinv, l15);
            ivv[1] = __shfl(myinv, 16 + l15);
            #pragma unroll
            for (int p2 = 0; p2 < 2; ++p2) {
                const int pxl = (2 * h + p2) * 16 + l15;
                const float iv = ivv[p2];
                float psum = 0.f;
                #pragma unroll
                for (int r = 0; r < 4; ++r) {
                    const int k = 16 * kt + 4 * q + r;
                    const float lv = acc1[p2][r] * iv;
                    __builtin_nontemporal_store(lv, &lgp[(size_t)k * P + pxl]);
                    const float e = __expf(fmaf(lv, ALPHA, bz[r]));
                    saf[k * 68 + pxl] = e;
                    psum += e;
                }
                denom[(4 * w + q) * 68 + pxl] = psum;
            }
        }
        bar_lds();                              // B3

        // ---- S + sa2 (thread = (k-row = lane, px-seg = w), 8 px each) ----
        {
            float dinv = 0.f;
            if (lane < 8) {
                const int px = 8 * w + lane;
                const int H = px >> 5;
                float dd = 0.f;
                #pragma unroll
                for (int t = 0; t < 4; ++t)
                    #pragma unroll
                    for (int qq = 0; qq < 4; ++qq)
                        dd += denom[(8 * t + 4 * H + qq) * 68 + px];
                dinv = 1.0f / dd;
            }
            const float* sp = &saf[lane * 68 + 8 * w];
            const f4 ivA = *(const f4*)&invs[8 * w];
            const f4 ivB = *(const f4*)&invs[8 * w + 4];
            float s = 0.f;
            unsigned pk[4];
            #pragma unroll
            for (int m = 0; m < 2; ++m) {
                f4 e = *(const f4*)&sp[4 * m];
                const f4 iv = m ? ivB : ivA;
                const float r0 = __shfl(dinv, 4 * m + 0);
                const float r1 = __shfl(dinv, 4 * m + 1);
                const float r2 = __shfl(dinv, 4 * m + 2);
                const float r3 = __shfl(dinv, 4 * m + 3);
                s += e[0] * r0; s += e[1] * r1;
                s += e[2] * r2; s += e[3] * r3;
                const float v0 = e[0] * (r0 * iv[0]);
                const float v1 = e[1] * (r1 * iv[1]);
                const float v2 = e[2] * (r2 * iv[2]);
                const float v3 = e[3] * (r3 * iv[3]);
                pk[2 * m]     = cvtpk(v0, v1);
                pk[2 * m + 1] = cvtpk(v2, v3);
            }
            Sreg += s;
            *(u32x4*)&sa2s[lane * 72 + 8 * w] = (u32x4){pk[0], pk[1], pk[2], pk[3]};
        }
        bar_lds();                              // B4

        // ---- GEMM2: acc2[kt-tile][c-tile] += sa2 . x_raw ----
        {
            short8_t a2[2];
            #pragma unroll
            for (int kit = 0; kit < 2; ++kit)
                a2[kit] = *(const short8_t*)&sa2s[(16 * kt + l15) * 72 + kit * 32 + 8 * q];
            __builtin_amdgcn_s_setprio(1);
            #pragma unroll
            for (int ctl = 0; ctl < 4; ++ctl) {
                const int ct = 4 * h + ctl;
                #pragma unroll
                for (int kit = 0; kit < 2; ++kit) {
                    const unsigned short* bp = &xsN[(ct * 16 + l15) * 76 + kit * 32 + 8 * q];
                    short4_t b0 = *(const short4_t*)bp;
                    short4_t b1 = *(const short4_t*)(bp + 4);
                    short8_t bb;
                    bb[0] = b0[0]; bb[1] = b0[1]; bb[2] = b0[2]; bb[3] = b0[3];
                    bb[4] = b1[0]; bb[5] = b1[1]; bb[6] = b1[2]; bb[7] = b1[3];
                    acc2[ctl] = __builtin_amdgcn_mfma_f32_16x16x32_bf16(a2[kit], bb, acc2[ctl], 0, 0, 0);
                }
            }
            __builtin_amdgcn_s_setprio(0);
        }

        if (ch < 7) {
            #pragma unroll
            for (int j = 0; j < 4; ++j) va[j] = vb[j];
        }
    }

    // ---- epilogue: per-block partials (no atomics) ----
    float* vp = vlad_part + ((size_t)blk8 * N + n) * (size_t)(K * C);
    #pragma unroll
    for (int ctl = 0; ctl < 4; ++ctl)
        #pragma unroll
        for (int r = 0; r < 4; ++r)
            vp[(16 * kt + 4 * q + r) * C + (4 * h + ctl) * 16 + l15] = acc2[ctl][r];

    __syncthreads();                 // denom region reused as red[512]
    red[tid] = Sreg;
    __syncthreads();
    if (tid < 64) {
        float s = 0.f;
        #pragma unroll
        for (int p = 0; p < 8; ++p) s += red[64 * p + tid];
        Spart[((size_t)blk8 * N + n) * K + tid] = s;
    }
}

// ---------------------------------------------------------------------------
// Post 1: 512 blocks (n x 8 k-rows). Reduce 8 partials, subtract W*S,
// intra-norm (c); 32-lane shuffle reduce; atomicAdd ss2 partial.
// ---------------------------------------------------------------------------
__global__ __launch_bounds__(256) void k_post1(
    const float* __restrict__ vlad_part, const float* __restrict__ W,
    const float* __restrict__ Spart, float* __restrict__ out,
    float* __restrict__ ss2acc)
{
    __shared__ float red[8];
    const int tid = threadIdx.x;
    const int n  = blockIdx.x >> 3;
    const int kq = blockIdx.x & 7;
    const int kl = tid >> 5;           // 0..7
    const int ci = tid & 31;           // 0..31
    const int k  = kq * 8 + kl;
    const int c0 = ci * 4;

    float Sk = 0.f;
    #pragma unroll
    for (int ch = 0; ch < NCH2; ++ch) Sk += Spart[(size_t)(ch * N + n) * K + k];

    float v[4];
    #pragma unroll
    for (int l = 0; l < 4; ++l) v[l] = 0.f;
    #pragma unroll
    for (int ch = 0; ch < NCH2; ++ch) {
        const float* vp = vlad_part + ((size_t)(ch * N + n) * K + k) * C + c0;
        float4 a = *(const float4*)&vp[0];
        v[0] += a.x; v[1] += a.y; v[2] += a.z; v[3] += a.w;
    }

    float ss = 0.f;
    #pragma unroll
    for (int l = 0; l < 4; ++l) {
        float val = v[l] - W[(size_t)(c0 + l) * K + k] * Sk;
        v[l] = val;
        ss = fmaf(val, val, ss);
    }
    ss += __shfl_xor(ss, 1);
    ss += __shfl_xor(ss, 2);
    ss += __shfl_xor(ss, 4);
    ss += __shfl_xor(ss, 8);
    ss += __shfl_xor(ss, 16);
    const float inv1 = 1.0f / fmaxf(sqrtf(ss), EPS);
    float ss2 = 0.f;
    #pragma unroll
    for (int l = 0; l < 4; ++l) { v[l] *= inv1; ss2 = fmaf(v[l], v[l], ss2); }
    ss2 += __shfl_xor(ss2, 1);
    ss2 += __shfl_xor(ss2, 2);
    ss2 += __shfl_xor(ss2, 4);
    ss2 += __shfl_xor(ss2, 8);
    ss2 += __shfl_xor(ss2, 16);
    if (ci == 0) red[kl] = ss2;
    __syncthreads();
    if (tid == 0) {
        float t = 0.f;
        #pragma unroll
        for (int i = 0; i < 8; ++i) t += red[i];
        atomicAdd(&ss2acc[n], t);
    }

    float* op = out + (size_t)n * K * C + (size_t)k * C + c0;
    *(float4*)&op[0] = (float4){v[0], v[1], v[2], v[3]};
}

// ---------------------------------------------------------------------------
// Post 2: global L2 rescale in place. grid = N*4.
// ---------------------------------------------------------------------------
__global__ __launch_bounds__(256) void k_post2(
    float* __restrict__ out, const float* __restrict__ ss2acc)
{
    const int n   = blockIdx.x >> 2;
    const int seg = blockIdx.x & 3;
    const float inv2 = 1.0f / fmaxf(sqrtf(ss2acc[n]), EPS);
    float* p = out + (size_t)n * K * C + (size_t)seg * 2048 + (size_t)threadIdx.x * 8;
    float4 a = *(const float4*)&p[0];
    float4 b = *(const float4*)&p[4];
    a.x *= inv2; a.y *= inv2; a.z *= inv2; a.w *= inv2;
    b.x *= inv2; b.y *= inv2; b.z *= inv2; b.w *= inv2;
    *(float4*)&p[0] = a;
    *(float4*)&p[4] = b;
}

// ---------------------------------------------------------------------------
extern "C" void kernel_launch(void* const* d_in, const int* in_sizes, int n_in,
                              void* d_out, int out_size, void* d_ws, size_t ws_size,
                              hipStream_t stream)
{
    const float* x    = (const float*)d_in[0];
    const float* W    = (const float*)d_in[1];
    const float* bias = (const float*)d_in[2];

    float* out_vlad   = (float*)d_out;                       // N*K*C
    float* out_logits = (float*)d_out + (size_t)N * K * C;   // N*K*P

    float* ss2acc     = (float*)((char*)d_ws + 16384);                  // 256 B
    float* Spart      = (float*)((char*)d_ws + 32768);                  // 128 KiB
    float* vlad_part  = (float*)((char*)d_ws + 32768 + 131072);         // 16 MiB

    k_fused<<<dim3(N * NCH2), dim3(512), 0, stream>>>(
        x, W, bias, out_logits, vlad_part, Spart, ss2acc);
    k_post1<<<dim3(N * 8), dim3(256), 0, stream>>>(vlad_part, W, Spart, out_vlad, ss2acc);
    k_post2<<<dim3(N * 4), dim3(256), 0, stream>>>(out_vlad, ss2acc);
}

// Round 8
// 235.863 us; speedup vs baseline: 1.0397x; 1.0077x over previous
//
#include <hip/hip_runtime.h>
#include <math.h>

#define ALPHA 50.0f
#define EPS 1e-12f

constexpr int N = 64, C = 128, P = 4096, K = 64;
constexpr int NCH2 = 8;           // partial groups (one per block per n)

typedef short short8_t __attribute__((ext_vector_type(8)));
typedef short short4_t __attribute__((ext_vector_type(4)));
typedef float f4 __attribute__((ext_vector_type(4)));
typedef unsigned int u32x4 __attribute__((ext_vector_type(4)));
typedef unsigned int u32x2 __attribute__((ext_vector_type(2)));

__device__ __forceinline__ unsigned short f2bf(float f) {
    union { float f; unsigned u; } v; v.f = f;
    unsigned r = (v.u + 0x7FFFu + ((v.u >> 16) & 1u)) >> 16;   // RNE
    return (unsigned short)r;
}

// packed f32x2 -> bf16x2 (RNE), single VALU op
__device__ __forceinline__ unsigned cvtpk(float lo, float hi) {
    unsigned r;
    asm("v_cvt_pk_bf16_f32 %0, %1, %2" : "=v"(r) : "v"(lo), "v"(hi));
    return r;
}

// __syncthreads() minus the vmcnt(0) drain: LDS-visibility barrier only.
__device__ __forceinline__ void bar_lds() {
    asm volatile("s_waitcnt lgkmcnt(0)" ::: "memory");
    __builtin_amdgcn_s_barrier();
}

// ---------------------------------------------------------------------------
// Fused, wave-autonomous: 512 blocks x 256 threads. Block = (n, 512-px strip),
// 8 chunks of 64 px; wave w owns px sub-group [16w,16w+16) of every chunk.
// Per chunk only TWO barriers:
//   [stage own xsT slice + shared xsN | ssq+invs via shfl (in-wave) |
//    GEMM1 from own slice (A=full Wn in 64 VGPRs) | softmax fully in-reg
//    (denom = 2 shfl_xor) | logits NT | sa2 -> sa2s]   B1
//   [GEMM2 (k-split across waves, as rd4)]              B2
// S accumulated per-lane in regs, reduced once in epilogue.
// ---------------------------------------------------------------------------
__global__ __launch_bounds__(256, 2) void k_fused(
    const float* __restrict__ x, const float* __restrict__ W,
    const float* __restrict__ bias, float* __restrict__ logits,
    float* __restrict__ vlad_part, float* __restrict__ Spart,
    float* __restrict__ ss2acc)
{
    __shared__ __align__(16) char smem[47616];
    unsigned short* xsT  = (unsigned short*)smem;            // [4 w][16 px][136 c] bf16, 17408 B
    unsigned short* xsN  = (unsigned short*)(smem + 17408);  // [128 c][76 px] bf16, 19456 B
    unsigned short* sa2s = (unsigned short*)(smem + 36864);  // [64 k][72 px] bf16, 9216 B
    float*          biass= (float*)(smem + 46080);           // 64 f
    float*          Sb2  = (float*)(smem + 46336);           // [4][64] f32 (epilogue) / red[256] (prologue)
    float*          red  = Sb2;
    float*          cinv = (float*)(smem + 47360);           // 64 f
    float*          Wl   = (float*)smem;                     // prologue: [128][68] f32 = 34816 B

    const int tid  = threadIdx.x;
    const int n    = blockIdx.x >> 3;
    const int blk8 = blockIdx.x & 7;
    const int pbase = blk8 * 512;

    const int w = tid >> 6, lane = tid & 63;
    const int q = lane >> 4, l15 = lane & 15;
    const int c2 = lane >> 2, px4 = lane & 3;    // staging roles: c' 0..15, px-quad 0..3

    if (blockIdx.x == 0 && tid < 64) ss2acc[tid] = 0.f;   // k_post1 accumulator
    if (tid < K) biass[tid] = bias[tid] * ALPHA;

    // per-lane global base: c = 8*c2 + j rows, px = 16w + 4*px4 (+i)
    const float* xw = x + (size_t)n * C * P + pbase + 16 * w + 4 * px4 + (size_t)(8 * c2) * P;
    float4 va[8];
    short8_t af[4][4];      // A-frags for ALL 4 k-tiles x 4 c-steps (64 VGPR)
    float bzv[16];

    // ---- prologue: Wn fragments (all k-tiles) + chunk-0 x prefetch ----
    {
        float4 wv[8];
        #pragma unroll
        for (int it = 0; it < 8; ++it)
            wv[it] = *(const float4*)&W[(size_t)(tid + it * 256) * 4];
        #pragma unroll
        for (int j = 0; j < 8; ++j) va[j] = *(const float4*)&xw[(size_t)j * P];
        #pragma unroll
        for (int it = 0; it < 8; ++it) {
            const int idx4 = tid + it * 256;          // float4 index into W[C][K]
            *(float4*)&Wl[(idx4 >> 4) * 68 + (idx4 & 15) * 4] = wv[it];
        }
        bar_lds();
        {   // column sum-of-squares (order-identical to rd4)
            const int k = tid & 63, part = tid >> 6;
            float s = 0.f;
            #pragma unroll
            for (int i = 0; i < 32; ++i) {
                float v = Wl[(part * 32 + i) * 68 + k];
                s = fmaf(v, v, s);
            }
            red[tid] = s;
        }
        bar_lds();
        if (tid < 64)
            cinv[tid] = 1.0f / fmaxf(
                sqrtf(red[tid] + red[64 + tid] + red[128 + tid] + red[192 + tid]), EPS);
        bar_lds();
        #pragma unroll
        for (int kt = 0; kt < 4; ++kt) {
            const float cv = cinv[16 * kt + l15];
            #pragma unroll
            for (int s = 0; s < 4; ++s)
                #pragma unroll
                for (int j = 0; j < 8; ++j)
                    af[kt][s][j] = (short)f2bf(
                        Wl[(s * 32 + 8 * q + j) * 68 + 16 * kt + l15] * cv);
            #pragma unroll
            for (int r = 0; r < 4; ++r) bzv[4 * kt + r] = biass[16 * kt + 4 * q + r];
        }
        bar_lds();   // drain before staging(0) overwrites Wl
    }

    f4 acc2[8];
    #pragma unroll
    for (int ct = 0; ct < 8; ++ct) acc2[ct] = (f4){0.f, 0.f, 0.f, 0.f};
    float Sreg[16];
    #pragma unroll
    for (int i = 0; i < 16; ++i) Sreg[i] = 0.f;

    unsigned short* xsTw = xsT + w * 2176;   // own slice, 16 rows x 136 shorts

    for (int ch = 0; ch < 8; ++ch) {
        const float* vf = (const float*)va;

        // ---- in-wave ssq + invs (no LDS) ----
        float pss[4] = {0.f, 0.f, 0.f, 0.f};
        #pragma unroll
        for (int j = 0; j < 8; ++j)
            #pragma unroll
            for (int i = 0; i < 4; ++i)
                pss[i] = fmaf(vf[j * 4 + i], vf[j * 4 + i], pss[i]);
        #pragma unroll
        for (int i = 0; i < 4; ++i) {
            pss[i] += __shfl_xor(pss[i], 4);
            pss[i] += __shfl_xor(pss[i], 8);
            pss[i] += __shfl_xor(pss[i], 16);
            pss[i] += __shfl_xor(pss[i], 32);
        }
        float iv4[4];
        #pragma unroll
        for (int i = 0; i < 4; ++i) iv4[i] = 1.0f / fmaxf(sqrtf(pss[i]), EPS);

        // ---- stage own xsT slice (XOR-swizzled 16B blocks) + shared xsN ----
        #pragma unroll
        for (int i = 0; i < 4; ++i) {
            u32x4 t;
            #pragma unroll
            for (int jj = 0; jj < 4; ++jj)
                t[jj] = cvtpk(vf[(2 * jj) * 4 + i], vf[(2 * jj + 1) * 4 + i]);
            const int row = 4 * px4 + i;
            *(u32x4*)&xsTw[row * 136 + 8 * (c2 ^ (row & 7))] = t;
        }
        #pragma unroll
        for (int j = 0; j < 8; ++j) {
            u32x2 t2;
            t2[0] = cvtpk(vf[j * 4 + 0], vf[j * 4 + 1]);
            t2[1] = cvtpk(vf[j * 4 + 2], vf[j * 4 + 3]);
            *(u32x2*)&xsN[(8 * c2 + j) * 76 + 16 * w + 4 * px4] = t2;
        }
        if (ch < 7) {   // next-chunk loads: in flight under GEMM1+softmax+GEMM2
            #pragma unroll
            for (int j = 0; j < 8; ++j)
                va[j] = *(const float4*)&xw[(size_t)j * P + (ch + 1) * 64];
        }
        asm volatile("s_waitcnt lgkmcnt(0)" ::: "memory");  // own-slice w->r order
        __builtin_amdgcn_sched_barrier(0);                  // rule-18 hardening

        // ---- GEMM1 from own slice: 4 B-reads total, A in regs ----
        f4 acc1[4];
        #pragma unroll
        for (int t = 0; t < 4; ++t) acc1[t] = (f4){0.f, 0.f, 0.f, 0.f};
        __builtin_amdgcn_s_setprio(1);
        #pragma unroll
        for (int s = 0; s < 4; ++s) {
            short8_t bf = *(const short8_t*)&xsTw[l15 * 136 + 8 * ((4 * s + q) ^ (l15 & 7))];
            #pragma unroll
            for (int kt = 0; kt < 4; ++kt)
                acc1[kt] = __builtin_amdgcn_mfma_f32_16x16x32_bf16(af[kt][s], bf, acc1[kt], 0, 0, 0);
        }
        __builtin_amdgcn_s_setprio(0);

        // ---- fully in-register softmax ----
        const float s0 = __shfl(iv4[0], l15 >> 2);
        const float s1 = __shfl(iv4[1], l15 >> 2);
        const float s2 = __shfl(iv4[2], l15 >> 2);
        const float s3 = __shfl(iv4[3], l15 >> 2);
        const int li = l15 & 3;
        const float myiv = (li == 0) ? s0 : (li == 1) ? s1 : (li == 2) ? s2 : s3;

        float* lgp = logits + (size_t)n * K * P + pbase + ch * 64 + 16 * w + l15;
        float ev[16];
        float dl = 0.f;
        #pragma unroll
        for (int kt = 0; kt < 4; ++kt)
            #pragma unroll
            for (int r = 0; r < 4; ++r) {
                const float lv = acc1[kt][r] * myiv;
                __builtin_nontemporal_store(lv, &lgp[(size_t)(16 * kt + 4 * q + r) * P]);
                const float e = __expf(fmaf(lv, ALPHA, bzv[4 * kt + r]));
                ev[4 * kt + r] = e;
                dl += e;
            }
        dl += __shfl_xor(dl, 16);
        dl += __shfl_xor(dl, 32);
        const float rf = 1.0f / dl;
        const float sc = rf * myiv;
        #pragma unroll
        for (int kt = 0; kt < 4; ++kt)
            #pragma unroll
            for (int r = 0; r < 4; ++r) {
                const float e = ev[4 * kt + r];
                Sreg[4 * kt + r] += e * rf;
                sa2s[(16 * kt + 4 * q + r) * 72 + 16 * w + l15] = f2bf(e * sc);
            }
        bar_lds();                              // B1: sa2s + xsN visible

        // ---- GEMM2 (kt = w), exactly rd4 ----
        {
            short8_t a2[2];
            #pragma unroll
            for (int kit = 0; kit < 2; ++kit)
                a2[kit] = *(const short8_t*)&sa2s[(16 * w + l15) * 72 + kit * 32 + 8 * q];
            __builtin_amdgcn_s_setprio(1);
            #pragma unroll
            for (int ct = 0; ct < 8; ++ct)
                #pragma unroll
                for (int kit = 0; kit < 2; ++kit) {
                    const unsigned short* bp = &xsN[(ct * 16 + l15) * 76 + kit * 32 + 8 * q];
                    short4_t b0 = *(const short4_t*)bp;
                    short4_t b1 = *(const short4_t*)(bp + 4);
                    short8_t bb;
                    bb[0] = b0[0]; bb[1] = b0[1]; bb[2] = b0[2]; bb[3] = b0[3];
                    bb[4] = b1[0]; bb[5] = b1[1]; bb[6] = b1[2]; bb[7] = b1[3];
                    acc2[ct] = __builtin_amdgcn_mfma_f32_16x16x32_bf16(a2[kit], bb, acc2[ct], 0, 0, 0);
                }
            __builtin_amdgcn_s_setprio(0);
        }
        bar_lds();                              // B2: reuse guard
    }

    // ---- epilogue: vlad partials + in-reg S reduce ----
    float* vp = vlad_part + ((size_t)blk8 * N + n) * (size_t)(K * C);
    #pragma unroll
    for (int ct = 0; ct < 8; ++ct)
        #pragma unroll
        for (int r = 0; r < 4; ++r)
            vp[(16 * w + 4 * q + r) * C + ct * 16 + l15] = acc2[ct][r];

    #pragma unroll
    for (int i = 0; i < 16; ++i) {
        Sreg[i] += __shfl_xor(Sreg[i], 1);
        Sreg[i] += __shfl_xor(Sreg[i], 2);
        Sreg[i] += __shfl_xor(Sreg[i], 4);
        Sreg[i] += __shfl_xor(Sreg[i], 8);
    }
    if (l15 == 0) {
        #pragma unroll
        for (int i = 0; i < 16; ++i)
            Sb2[w * 64 + 16 * (i >> 2) + 4 * q + (i & 3)] = Sreg[i];
    }
    __syncthreads();
    if (tid < 64)
        Spart[((size_t)blk8 * N + n) * K + tid] =
            Sb2[tid] + Sb2[64 + tid] + Sb2[128 + tid] + Sb2[192 + tid];
}

// ---------------------------------------------------------------------------
// Post 1: 512 blocks (n x 8 k-rows). Reduce 8 partials, subtract W*S,
// intra-norm (c); 32-lane shuffle reduce; atomicAdd ss2 partial.
// ---------------------------------------------------------------------------
__global__ __launch_bounds__(256) void k_post1(
    const float* __restrict__ vlad_part, const float* __restrict__ W,
    const float* __restrict__ Spart, float* __restrict__ out,
    float* __restrict__ ss2acc)
{
    __shared__ float red[8];
    const int tid = threadIdx.x;
    const int n  = blockIdx.x >> 3;
    const int kq = blockIdx.x & 7;
    const int kl = tid >> 5;           // 0..7
    const int ci = tid & 31;           // 0..31
    const int k  = kq * 8 + kl;
    const int c0 = ci * 4;

    float Sk = 0.f;
    #pragma unroll
    for (int ch = 0; ch < NCH2; ++ch) Sk += Spart[(size_t)(ch * N + n) * K + k];

    float v[4];
    #pragma unroll
    for (int l = 0; l < 4; ++l) v[l] = 0.f;
    #pragma unroll
    for (int ch = 0; ch < NCH2; ++ch) {
        const float* vp = vlad_part + ((size_t)(ch * N + n) * K + k) * C + c0;
        float4 a = *(const float4*)&vp[0];
        v[0] += a.x; v[1] += a.y; v[2] += a.z; v[3] += a.w;
    }

    float ss = 0.f;
    #pragma unroll
    for (int l = 0; l < 4; ++l) {
        float val = v[l] - W[(size_t)(c0 + l) * K + k] * Sk;
        v[l] = val;
        ss = fmaf(val, val, ss);
    }
    ss += __shfl_xor(ss, 1);
    ss += __shfl_xor(ss, 2);
    ss += __shfl_xor(ss, 4);
    ss += __shfl_xor(ss, 8);
    ss += __shfl_xor(ss, 16);
    const float inv1 = 1.0f / fmaxf(sqrtf(ss), EPS);
    float ss2 = 0.f;
    #pragma unroll
    for (int l = 0; l < 4; ++l) { v[l] *= inv1; ss2 = fmaf(v[l], v[l], ss2); }
    ss2 += __shfl_xor(ss2, 1);
    ss2 += __shfl_xor(ss2, 2);
    ss2 += __shfl_xor(ss2, 4);
    ss2 += __shfl_xor(ss2, 8);
    ss2 += __shfl_xor(ss2, 16);
    if (ci == 0) red[kl] = ss2;
    __syncthreads();
    if (tid == 0) {
        float t = 0.f;
        #pragma unroll
        for (int i = 0; i < 8; ++i) t += red[i];
        atomicAdd(&ss2acc[n], t);
    }

    float* op = out + (size_t)n * K * C + (size_t)k * C + c0;
    *(float4*)&op[0] = (float4){v[0], v[1], v[2], v[3]};
}

// ---------------------------------------------------------------------------
// Post 2: global L2 rescale in place. grid = N*4.
// ---------------------------------------------------------------------------
__global__ __launch_bounds__(256) void k_post2(
    float* __restrict__ out, const float* __restrict__ ss2acc)
{
    const int n   = blockIdx.x >> 2;
    const int seg = blockIdx.x & 3;
    const float inv2 = 1.0f / fmaxf(sqrtf(ss2acc[n]), EPS);
    float* p = out + (size_t)n * K * C + (size_t)seg * 2048 + (size_t)threadIdx.x * 8;
    float4 a = *(const float4*)&p[0];
    float4 b = *(const float4*)&p[4];
    a.x *= inv2; a.y *= inv2; a.z *= inv2; a.w *= inv2;
    b.x *= inv2; b.y *= inv2; b.z *= inv2; b.w *= inv2;
    *(float4*)&p[0] = a;
    *(float4*)&p[4] = b;
}

// ---------------------------------------------------------------------------
extern "C" void kernel_launch(void* const* d_in, const int* in_sizes, int n_in,
                              void* d_out, int out_size, void* d_ws, size_t ws_size,
                              hipStream_t stream)
{
    const float* x    = (const float*)d_in[0];
    const float* W    = (const float*)d_in[1];
    const float* bias = (const float*)d_in[2];

    float* out_vlad   = (float*)d_out;                       // N*K*C
    float* out_logits = (float*)d_out + (size_t)N * K * C;   // N*K*P

    float* ss2acc     = (float*)((char*)d_ws + 16384);                  // 256 B
    float* Spart      = (float*)((char*)d_ws + 32768);                  // 128 KiB
    float* vlad_part  = (float*)((char*)d_ws + 32768 + 131072);         // 16 MiB

    k_fused<<<dim3(N * NCH2), dim3(256), 0, stream>>>(
        x, W, bias, out_logits, vlad_part, Spart, ss2acc);
    k_post1<<<dim3(N * 8), dim3(256), 0, stream>>>(vlad_part, W, Spart, out_vlad, ss2acc);
    k_post2<<<dim3(N * 4), dim3(256), 0, stream>>>(out_vlad, ss2acc);
}